// Round 12
// baseline (85.979 us; speedup 1.0000x reference)
//
#include <hip/hip_runtime.h>
#include <hip/hip_bf16.h>

#define N_IN     512
#define N_OUTS   256
#define N_NODES  20000
#define N_EDGES  640000
#define N_LAYERS 6
#define BATCH    128
#define CHUNK    3248   // (N_NODES - N_IN) / N_LAYERS
#define L5_START 16752  // 512 + 5*3248
#define OUT_BASE (N_NODES - N_OUTS)   // 19744

#define NPART    8      // one dst-partition per XCD (scatter)
#define PART_SZ  2500   // ceil(N_NODES / NPART)
#define SCAT_NB  104    // slices per partition; scatter grid = 832

#define CSR_LOG2 7      // 128 slots/node; max degree ~ Poisson(33), P(>128) ~ 0
#define CSR_STRIDE (1 << CSR_LOG2)

typedef unsigned int   uint32;
typedef unsigned short ushort16;

// ---------------- workspace layout (bytes) ----------------
static constexpr size_t OFF_STATE = 0;                                  // ushort[N_NODES*BATCH]
static constexpr size_t OFF_CNT   = (size_t)N_NODES * BATCH * 2;        // int[N_NODES]
static constexpr size_t OFF_CSR   = OFF_CNT + (size_t)N_NODES * 4;      // uint[N_NODES*CSR_STRIDE]

__device__ __forceinline__ float bf16bits_to_f32(uint32 bits) {
    union { uint32 u; float f; } c; c.u = bits << 16; return c.f;
}
__device__ __forceinline__ ushort16 f32_to_bf16bits(float f) {
    union { float f; uint32 u; } c; c.f = f;
    uint32 lsb = (c.u >> 16) & 1u;
    c.u += 0x7FFFu + lsb;                 // round-to-nearest-even
    return (ushort16)(c.u >> 16);
}

// Wave-parallel f32-vs-bf16 self-detection (call with full wave active):
// a real-f32 array's first 64 halves contain ~uniform bits -> some half
// decodes (as bf16) to exponent >= 134 (P(miss)~1e-9, data fixed ->
// deterministic). Real N(0,1)-scale bf16 never has exponent >= 134.
__device__ __forceinline__ int detect_f32_wave(const ushort16* __restrict__ p) {
    int lane = threadIdx.x & 63;
    int ex = (p[lane] >> 7) & 0xFF;
    return __any(ex >= 134) ? 1 : 0;
}
// int64-vs-int32: dst values in [512, 20000): if int64, word 1 is 0.
__device__ __forceinline__ bool detect_i64(const int* __restrict__ dst32) {
    return dst32[1] == 0;
}

__device__ __forceinline__ float act_apply(int a, float x) {
    if (a == 0) return 1.f / (1.f + __expf(-x));   // sigmoid
    if (a == 1) return tanhf(x);                   // tanh
    return fmaxf(x, 0.f);                          // relu
}

// dead layer-5 nodes: in layer 5 but not an output node -> never read.
__device__ __forceinline__ bool is_dead(int d) {
    return d >= L5_START && d < OUT_BASE;
}

// ---------------- fused state-init + count+scatter into padded CSR ---------
// cnt pre-zeroed by hipMemsetAsync. State-init rides in the prologue (scatter
// never reads state; layer kernels see it via kernel-boundary coherence).
// blockIdx % 8 -> XCD (HW round-robin); block handles only dst-partition
// (bid&7): every CSR line written by exactly ONE XCD -> full-line L2
// evictions, no cross-XCD false sharing. Entry = (src<<16)|bf16_bits(w).
// Dead layer-5 dst are skipped (~15% of edges).
__global__ void k_scatter(const ushort16* __restrict__ xb,
                          const int* __restrict__ src32,
                          const int* __restrict__ dst32,
                          const ushort16* __restrict__ wraw,
                          ushort16* __restrict__ state,
                          int* __restrict__ cnt,
                          uint32* __restrict__ csr) {
    const int f32x = detect_f32_wave(xb);
    const int f32w = detect_f32_wave(wraw);
    {   // ---- state init: state[n][b] = bf16(x[b][n]) ----
        const int idx = blockIdx.x * 256 + threadIdx.x;
        if (idx < N_IN * BATCH) {
            int n = idx >> 7, b = idx & 127;
            state[idx] = f32x ? f32_to_bf16bits(((const float*)xb)[b * N_IN + n])
                              : xb[b * N_IN + n];
        }
    }
    const int part = blockIdx.x & (NPART - 1);
    const int slice = blockIdx.x >> 3;
    const int nthr = (gridDim.x >> 3) * 256;
    const int tid0 = slice * 256 + threadIdx.x;
    if (detect_i64(dst32)) {
        const int4* d4 = (const int4*)dst32;          // 2 int64 edges / 16B
        const int4* s4 = (const int4*)src32;
        for (int p = tid0; p < N_EDGES / 2; p += nthr) {
            int4 dq = d4[p];
            int d0 = dq.x, d1 = dq.z;
            bool m0 = (d0 / PART_SZ) == part && !is_dead(d0);
            bool m1 = (d1 / PART_SZ) == part && !is_dead(d1);
            if (!m0 && !m1) continue;
            int4 sq = s4[p];
            uint32 w0b, w1b;
            if (f32w) {
                float2 wf = ((const float2*)wraw)[p];
                w0b = f32_to_bf16bits(wf.x); w1b = f32_to_bf16bits(wf.y);
            } else {
                uint32 wb = ((const uint32*)wraw)[p];
                w0b = wb & 0xFFFFu; w1b = wb >> 16;
            }
            if (m0) {
                int pos = atomicAdd(&cnt[d0], 1);
                if (pos < CSR_STRIDE) csr[((size_t)d0 << CSR_LOG2) + pos] = ((uint32)sq.x << 16) | w0b;
            }
            if (m1) {
                int pos = atomicAdd(&cnt[d1], 1);
                if (pos < CSR_STRIDE) csr[((size_t)d1 << CSR_LOG2) + pos] = ((uint32)sq.z << 16) | w1b;
            }
        }
    } else {
        const int4* d4 = (const int4*)dst32;          // 4 int32 edges / 16B
        const int4* s4 = (const int4*)src32;
        for (int p = tid0; p < N_EDGES / 4; p += nthr) {
            int4 dq = d4[p];
            bool m0 = (dq.x / PART_SZ) == part && !is_dead(dq.x);
            bool m1 = (dq.y / PART_SZ) == part && !is_dead(dq.y);
            bool m2 = (dq.z / PART_SZ) == part && !is_dead(dq.z);
            bool m3 = (dq.w / PART_SZ) == part && !is_dead(dq.w);
            if (!(m0 | m1 | m2 | m3)) continue;
            int4 sq = s4[p];
            uint32 wb0, wb1, wb2, wb3;
            if (f32w) {
                float4 wf = ((const float4*)wraw)[p];
                wb0 = f32_to_bf16bits(wf.x); wb1 = f32_to_bf16bits(wf.y);
                wb2 = f32_to_bf16bits(wf.z); wb3 = f32_to_bf16bits(wf.w);
            } else {
                uint2 wu = ((const uint2*)wraw)[p];
                wb0 = wu.x & 0xFFFFu; wb1 = wu.x >> 16;
                wb2 = wu.y & 0xFFFFu; wb3 = wu.y >> 16;
            }
            if (m0) { int pos = atomicAdd(&cnt[dq.x], 1);
                      if (pos < CSR_STRIDE) csr[((size_t)dq.x << CSR_LOG2) + pos] = ((uint32)sq.x << 16) | wb0; }
            if (m1) { int pos = atomicAdd(&cnt[dq.y], 1);
                      if (pos < CSR_STRIDE) csr[((size_t)dq.y << CSR_LOG2) + pos] = ((uint32)sq.y << 16) | wb1; }
            if (m2) { int pos = atomicAdd(&cnt[dq.z], 1);
                      if (pos < CSR_STRIDE) csr[((size_t)dq.z << CSR_LOG2) + pos] = ((uint32)sq.z << 16) | wb2; }
            if (m3) { int pos = atomicAdd(&cnt[dq.w], 1);
                      if (pos < CSR_STRIDE) csr[((size_t)dq.w << CSR_LOG2) + pos] = ((uint32)sq.w << 16) | wb3; }
        }
    }
}

// ---------------- shared gather core (wave-per-node, uint32 loads) ---------
// Lane owns 2 batch elems: one 4B load per lane per edge = 256B/wave/request
// -> the full state row in ONE memory request (vs two 128B at 2B/lane).
// Same total bytes, HALF the request count: targets the per-CU outstanding-
// request-slot limit (R11 showed ILP depth 32 doesn't help; R10 queues were
// already oversubscribed). 16/4/1 tiers (R10-proven depth).
__device__ __forceinline__ void gather_acc2(int node, int lane,
                                            const uint32* __restrict__ state32,
                                            const int* __restrict__ cnt,
                                            const uint32* __restrict__ csr,
                                            float& acc0, float& acc1) {
    const int lo = node << CSR_LOG2;
    const int hi = lo + cnt[node];
    acc0 = 0.f; acc1 = 0.f;
    int e = lo;
    for (; e + 16 <= hi; e += 16) {           // 16 row-requests in flight
        uint32 p[16], rv[16];
#pragma unroll
        for (int k = 0; k < 16; ++k) p[k] = csr[e + k];
#pragma unroll
        for (int k = 0; k < 16; ++k)
            rv[k] = state32[((p[k] >> 16) << 6) + (uint32)lane];
#pragma unroll
        for (int k = 0; k < 16; ++k) {
            float w = bf16bits_to_f32(p[k] & 0xFFFFu);
            acc0 = fmaf(w, bf16bits_to_f32(rv[k] & 0xFFFFu), acc0);
            acc1 = fmaf(w, bf16bits_to_f32(rv[k] >> 16), acc1);
        }
    }
    for (; e + 4 <= hi; e += 4) {
        uint32 p[4], rv[4];
#pragma unroll
        for (int k = 0; k < 4; ++k) p[k] = csr[e + k];
#pragma unroll
        for (int k = 0; k < 4; ++k)
            rv[k] = state32[((p[k] >> 16) << 6) + (uint32)lane];
#pragma unroll
        for (int k = 0; k < 4; ++k) {
            float w = bf16bits_to_f32(p[k] & 0xFFFFu);
            acc0 = fmaf(w, bf16bits_to_f32(rv[k] & 0xFFFFu), acc0);
            acc1 = fmaf(w, bf16bits_to_f32(rv[k] >> 16), acc1);
        }
    }
    for (; e < hi; ++e) {
        uint32 p = csr[e];
        uint32 rv = state32[((p >> 16) << 6) + (uint32)lane];
        float w = bf16bits_to_f32(p & 0xFFFFu);
        acc0 = fmaf(w, bf16bits_to_f32(rv & 0xFFFFu), acc0);
        acc1 = fmaf(w, bf16bits_to_f32(rv >> 16), acc1);
    }
}

// ---------------- per-layer gather + activation (layers 0..4) --------------
// 4 nodes per 256-thread block; each wave owns one node; lane owns batch
// elems (2*lane, 2*lane+1). CHUNK = 3248 = 812 blocks exactly.
__global__ void __launch_bounds__(256)
k_layer(uint32* __restrict__ state32,
        const int* __restrict__ cnt,
        const uint32* __restrict__ csr,
        const int* __restrict__ act32,
        const int* __restrict__ dst32,
        int base) {
    const int wv = threadIdx.x >> 6;
    const int lane = threadIdx.x & 63;
    const int node = base + blockIdx.x * 4 + wv;
    const int istride = detect_i64(dst32) ? 2 : 1;
    const int a = act32[(size_t)node * istride];     // independent: issue early
    float acc0, acc1;
    gather_acc2(node, lane, state32, cnt, csr, acc0, acc1);
    uint32 res = (uint32)f32_to_bf16bits(act_apply(a, acc0))
               | ((uint32)f32_to_bf16bits(act_apply(a, acc1)) << 16);
    state32[((uint32)node << 6) + (uint32)lane] = res;
}

// ---------------- layer 5: ONLY the 256 output nodes, straight to out ------
// Reference returns state[:, -256:]; the other 2992 layer-5 nodes are dead.
// 64 blocks x 4 waves; wave owns output node j, lane owns batch pair.
__global__ void __launch_bounds__(256)
k_out_layer(const uint32* __restrict__ state32,
            const int* __restrict__ cnt,
            const uint32* __restrict__ csr,
            const int* __restrict__ act32,
            const int* __restrict__ dst32,
            const ushort16* __restrict__ xb,
            void* __restrict__ out) {
    const int f32x = detect_f32_wave(xb);
    const int wv = threadIdx.x >> 6;
    const int lane = threadIdx.x & 63;
    const int j = blockIdx.x * 4 + wv;        // 0..255
    const int node = OUT_BASE + j;
    const int istride = detect_i64(dst32) ? 2 : 1;
    const int a = act32[(size_t)node * istride];
    float acc0, acc1;
    gather_acc2(node, lane, state32, cnt, csr, acc0, acc1);
    // out[b][j], b = 2*lane (+1); round through bf16 to match state path
    ushort16 r0 = f32_to_bf16bits(act_apply(a, acc0));
    ushort16 r1 = f32_to_bf16bits(act_apply(a, acc1));
    const int b0 = 2 * lane;
    if (f32x) {
        ((float*)out)[(b0 << 8) | j]       = bf16bits_to_f32(r0);
        ((float*)out)[((b0 + 1) << 8) | j] = bf16bits_to_f32(r1);
    } else {
        ((ushort16*)out)[(b0 << 8) | j]       = r0;
        ((ushort16*)out)[((b0 + 1) << 8) | j] = r1;
    }
}

extern "C" void kernel_launch(void* const* d_in, const int* in_sizes, int n_in,
                              void* d_out, int out_size, void* d_ws, size_t ws_size,
                              hipStream_t stream) {
    const ushort16* x_raw = (const ushort16*)d_in[0];
    const ushort16* w_raw = (const ushort16*)d_in[1];
    const int* src32 = (const int*)d_in[2];
    const int* dst32 = (const int*)d_in[3];
    const int* act32 = (const int*)d_in[4];
    (void)d_in[5]; (void)d_in[6]; (void)in_sizes; (void)n_in; (void)out_size; (void)ws_size;

    char* ws = (char*)d_ws;
    ushort16* state = (ushort16*)(ws + OFF_STATE);
    int*    cnt = (int*)(ws + OFF_CNT);
    uint32* csr = (uint32*)(ws + OFF_CSR);

    hipMemsetAsync(cnt, 0, (size_t)N_NODES * 4, stream);

    k_scatter<<<NPART * SCAT_NB, 256, 0, stream>>>(x_raw, src32, dst32, w_raw,
                                                    state, cnt, csr);

    for (int l = 0; l < N_LAYERS - 1; ++l) {
        int base = N_IN + l * CHUNK;
        k_layer<<<CHUNK / 4, 256, 0, stream>>>((uint32*)state, cnt, csr,
                                               act32, dst32, base);
    }

    k_out_layer<<<N_OUTS / 4, 256, 0, stream>>>((uint32*)state, cnt, csr,
                                                act32, dst32, x_raw, d_out);
}

// Round 13
// 79.930 us; speedup vs baseline: 1.0757x; 1.0757x over previous
//
#include <hip/hip_runtime.h>
#include <hip/hip_bf16.h>

#define N_IN     512
#define N_OUTS   256
#define N_NODES  20000
#define N_EDGES  640000
#define N_LAYERS 6
#define BATCH    128
#define CHUNK    3248   // (N_NODES - N_IN) / N_LAYERS
#define L5_START 16752  // 512 + 5*3248
#define OUT_BASE (N_NODES - N_OUTS)   // 19744

#define NPART    8      // one dst-partition per XCD (scatter)
#define PART_SZ  2500   // ceil(N_NODES / NPART)
#define SCAT_NB  104    // slices per partition; scatter grid = 832

#define CSR_LOG2 7      // 128 slots/node; max degree ~ Poisson(33), P(>128) ~ 0
#define CSR_STRIDE (1 << CSR_LOG2)

typedef unsigned int   uint32;
typedef unsigned short ushort16;

// ---------------- workspace layout (bytes) ----------------
static constexpr size_t OFF_STATE = 0;                                  // ushort[N_NODES*BATCH]
static constexpr size_t OFF_CNT   = (size_t)N_NODES * BATCH * 2;        // int[N_NODES]
static constexpr size_t OFF_CSR   = OFF_CNT + (size_t)N_NODES * 4;      // uint[N_NODES*CSR_STRIDE]

__device__ __forceinline__ float bf16bits_to_f32(uint32 bits) {
    union { uint32 u; float f; } c; c.u = bits << 16; return c.f;
}
__device__ __forceinline__ ushort16 f32_to_bf16bits(float f) {
    union { float f; uint32 u; } c; c.f = f;
    uint32 lsb = (c.u >> 16) & 1u;
    c.u += 0x7FFFu + lsb;                 // round-to-nearest-even
    return (ushort16)(c.u >> 16);
}

// Wave-parallel f32-vs-bf16 self-detection (call with full wave active):
// a real-f32 array's first 64 halves contain ~uniform bits -> some half
// decodes (as bf16) to exponent >= 134 (P(miss)~1e-9, data fixed ->
// deterministic). Real N(0,1)-scale bf16 never has exponent >= 134.
__device__ __forceinline__ int detect_f32_wave(const ushort16* __restrict__ p) {
    int lane = threadIdx.x & 63;
    int ex = (p[lane] >> 7) & 0xFF;
    return __any(ex >= 134) ? 1 : 0;
}
// int64-vs-int32: dst values in [512, 20000): if int64, word 1 is 0.
__device__ __forceinline__ bool detect_i64(const int* __restrict__ dst32) {
    return dst32[1] == 0;
}

__device__ __forceinline__ float act_apply(int a, float x) {
    if (a == 0) return 1.f / (1.f + __expf(-x));   // sigmoid
    if (a == 1) return tanhf(x);                   // tanh
    return fmaxf(x, 0.f);                          // relu
}

// dead layer-5 nodes: in layer 5 but not an output node -> never read.
__device__ __forceinline__ bool is_dead(int d) {
    return d >= L5_START && d < OUT_BASE;
}

// ---------------- fused state-init + count+scatter into padded CSR ---------
// cnt pre-zeroed by hipMemsetAsync. State-init rides in the prologue (scatter
// never reads state; layer kernels see it via kernel-boundary coherence).
// blockIdx % 8 -> XCD (HW round-robin); block handles only dst-partition
// (bid&7): every CSR line written by exactly ONE XCD -> full-line L2
// evictions, no cross-XCD false sharing. Entry = (src<<16)|bf16_bits(w).
// Dead layer-5 dst are skipped (~15% of edges).
__global__ void k_scatter(const ushort16* __restrict__ xb,
                          const int* __restrict__ src32,
                          const int* __restrict__ dst32,
                          const ushort16* __restrict__ wraw,
                          ushort16* __restrict__ state,
                          int* __restrict__ cnt,
                          uint32* __restrict__ csr) {
    const int f32x = detect_f32_wave(xb);
    const int f32w = detect_f32_wave(wraw);
    {   // ---- state init: state[n][b] = bf16(x[b][n]) ----
        const int idx = blockIdx.x * 256 + threadIdx.x;
        if (idx < N_IN * BATCH) {
            int n = idx >> 7, b = idx & 127;
            state[idx] = f32x ? f32_to_bf16bits(((const float*)xb)[b * N_IN + n])
                              : xb[b * N_IN + n];
        }
    }
    const int part = blockIdx.x & (NPART - 1);
    const int slice = blockIdx.x >> 3;
    const int nthr = (gridDim.x >> 3) * 256;
    const int tid0 = slice * 256 + threadIdx.x;
    if (detect_i64(dst32)) {
        const int4* d4 = (const int4*)dst32;          // 2 int64 edges / 16B
        const int4* s4 = (const int4*)src32;
        for (int p = tid0; p < N_EDGES / 2; p += nthr) {
            int4 dq = d4[p];
            int d0 = dq.x, d1 = dq.z;
            bool m0 = (d0 / PART_SZ) == part && !is_dead(d0);
            bool m1 = (d1 / PART_SZ) == part && !is_dead(d1);
            if (!m0 && !m1) continue;
            int4 sq = s4[p];
            uint32 w0b, w1b;
            if (f32w) {
                float2 wf = ((const float2*)wraw)[p];
                w0b = f32_to_bf16bits(wf.x); w1b = f32_to_bf16bits(wf.y);
            } else {
                uint32 wb = ((const uint32*)wraw)[p];
                w0b = wb & 0xFFFFu; w1b = wb >> 16;
            }
            if (m0) {
                int pos = atomicAdd(&cnt[d0], 1);
                if (pos < CSR_STRIDE) csr[((size_t)d0 << CSR_LOG2) + pos] = ((uint32)sq.x << 16) | w0b;
            }
            if (m1) {
                int pos = atomicAdd(&cnt[d1], 1);
                if (pos < CSR_STRIDE) csr[((size_t)d1 << CSR_LOG2) + pos] = ((uint32)sq.z << 16) | w1b;
            }
        }
    } else {
        const int4* d4 = (const int4*)dst32;          // 4 int32 edges / 16B
        const int4* s4 = (const int4*)src32;
        for (int p = tid0; p < N_EDGES / 4; p += nthr) {
            int4 dq = d4[p];
            bool m0 = (dq.x / PART_SZ) == part && !is_dead(dq.x);
            bool m1 = (dq.y / PART_SZ) == part && !is_dead(dq.y);
            bool m2 = (dq.z / PART_SZ) == part && !is_dead(dq.z);
            bool m3 = (dq.w / PART_SZ) == part && !is_dead(dq.w);
            if (!(m0 | m1 | m2 | m3)) continue;
            int4 sq = s4[p];
            uint32 wb0, wb1, wb2, wb3;
            if (f32w) {
                float4 wf = ((const float4*)wraw)[p];
                wb0 = f32_to_bf16bits(wf.x); wb1 = f32_to_bf16bits(wf.y);
                wb2 = f32_to_bf16bits(wf.z); wb3 = f32_to_bf16bits(wf.w);
            } else {
                uint2 wu = ((const uint2*)wraw)[p];
                wb0 = wu.x & 0xFFFFu; wb1 = wu.x >> 16;
                wb2 = wu.y & 0xFFFFu; wb3 = wu.y >> 16;
            }
            if (m0) { int pos = atomicAdd(&cnt[dq.x], 1);
                      if (pos < CSR_STRIDE) csr[((size_t)dq.x << CSR_LOG2) + pos] = ((uint32)sq.x << 16) | wb0; }
            if (m1) { int pos = atomicAdd(&cnt[dq.y], 1);
                      if (pos < CSR_STRIDE) csr[((size_t)dq.y << CSR_LOG2) + pos] = ((uint32)sq.y << 16) | wb1; }
            if (m2) { int pos = atomicAdd(&cnt[dq.z], 1);
                      if (pos < CSR_STRIDE) csr[((size_t)dq.z << CSR_LOG2) + pos] = ((uint32)sq.z << 16) | wb2; }
            if (m3) { int pos = atomicAdd(&cnt[dq.w], 1);
                      if (pos < CSR_STRIDE) csr[((size_t)dq.w << CSR_LOG2) + pos] = ((uint32)sq.w << 16) | wb3; }
        }
    }
}

// ---------------- shared gather core: sum over a node's CSR entries --------
// R10-proven: 16/4/1 tiers, 2B/lane loads, 128-thr/node (max TLP: 6496
// waves/layer). R11 (32-deep) and R12 (wave/node 4B-lane) both regressed —
// TLP is the binding resource for this latency-bound random gather.
__device__ __forceinline__ float gather_acc(int node, int b,
                                            const ushort16* __restrict__ state,
                                            const int* __restrict__ cnt,
                                            const uint32* __restrict__ csr) {
    const int lo = node << CSR_LOG2;
    const int hi = lo + cnt[node];
    float acc = 0.f;
    int e = lo;
    for (; e + 16 <= hi; e += 16) {           // 16 gathers in flight
        uint32 p[16]; float v[16];
#pragma unroll
        for (int k = 0; k < 16; ++k) p[k] = csr[e + k];
#pragma unroll
        for (int k = 0; k < 16; ++k)
            v[k] = bf16bits_to_f32(state[(size_t)(p[k] >> 16) * BATCH + b]);
#pragma unroll
        for (int k = 0; k < 16; ++k)
            acc = fmaf(bf16bits_to_f32(p[k] & 0xFFFFu), v[k], acc);
    }
    for (; e + 4 <= hi; e += 4) {
        uint32 p[4]; float v[4];
#pragma unroll
        for (int k = 0; k < 4; ++k) p[k] = csr[e + k];
#pragma unroll
        for (int k = 0; k < 4; ++k)
            v[k] = bf16bits_to_f32(state[(size_t)(p[k] >> 16) * BATCH + b]);
#pragma unroll
        for (int k = 0; k < 4; ++k)
            acc = fmaf(bf16bits_to_f32(p[k] & 0xFFFFu), v[k], acc);
    }
    for (; e < hi; ++e) {
        uint32 p = csr[e];
        float v = bf16bits_to_f32(state[(size_t)(p >> 16) * BATCH + b]);
        acc = fmaf(bf16bits_to_f32(p & 0xFFFFu), v, acc);
    }
    return acc;
}

// ---------------- per-layer gather + activation (layers 0..4) --------------
// one block (128 threads = 2 waves) per node; thread = batch lane; f32
// register accum. Independent act load hoisted ahead of the gather.
__global__ void __launch_bounds__(BATCH)
k_layer(ushort16* __restrict__ state,
        const int* __restrict__ cnt,
        const uint32* __restrict__ csr,
        const int* __restrict__ act32,
        const int* __restrict__ dst32,
        int base) {
    const int node = base + blockIdx.x;
    const int b = threadIdx.x;
    const int istride = detect_i64(dst32) ? 2 : 1;
    const int a = act32[(size_t)node * istride];     // independent: issue early
    float acc = gather_acc(node, b, state, cnt, csr);
    state[(size_t)node * BATCH + b] = f32_to_bf16bits(act_apply(a, acc));
}

// ---------------- layer 5: ONLY the 256 output nodes, straight to out ------
// Reference returns state[:, -256:]; the other 2992 layer-5 nodes are dead.
__global__ void __launch_bounds__(BATCH)
k_out_layer(const ushort16* __restrict__ state,
            const int* __restrict__ cnt,
            const uint32* __restrict__ csr,
            const int* __restrict__ act32,
            const int* __restrict__ dst32,
            const ushort16* __restrict__ xb,
            void* __restrict__ out) {
    const int f32x = detect_f32_wave(xb);
    const int j = blockIdx.x;                 // 0..255
    const int node = OUT_BASE + j;
    const int b = threadIdx.x;
    const int istride = detect_i64(dst32) ? 2 : 1;
    const int a = act32[(size_t)node * istride];
    float acc = gather_acc(node, b, state, cnt, csr);
    float r = act_apply(a, acc);
    // out[b][j]; round through bf16 to match the stored-state path exactly
    ushort16 rb = f32_to_bf16bits(r);
    if (f32x) ((float*)out)[(b << 8) | j] = bf16bits_to_f32(rb);
    else      ((ushort16*)out)[(b << 8) | j] = rb;
}

extern "C" void kernel_launch(void* const* d_in, const int* in_sizes, int n_in,
                              void* d_out, int out_size, void* d_ws, size_t ws_size,
                              hipStream_t stream) {
    const ushort16* x_raw = (const ushort16*)d_in[0];
    const ushort16* w_raw = (const ushort16*)d_in[1];
    const int* src32 = (const int*)d_in[2];
    const int* dst32 = (const int*)d_in[3];
    const int* act32 = (const int*)d_in[4];
    (void)d_in[5]; (void)d_in[6]; (void)in_sizes; (void)n_in; (void)out_size; (void)ws_size;

    char* ws = (char*)d_ws;
    ushort16* state = (ushort16*)(ws + OFF_STATE);
    int*    cnt = (int*)(ws + OFF_CNT);
    uint32* csr = (uint32*)(ws + OFF_CSR);

    hipMemsetAsync(cnt, 0, (size_t)N_NODES * 4, stream);

    k_scatter<<<NPART * SCAT_NB, 256, 0, stream>>>(x_raw, src32, dst32, w_raw,
                                                    state, cnt, csr);

    for (int l = 0; l < N_LAYERS - 1; ++l) {
        int base = N_IN + l * CHUNK;
        k_layer<<<CHUNK, BATCH, 0, stream>>>(state, cnt, csr, act32, dst32, base);
    }

    k_out_layer<<<N_OUTS, BATCH, 0, stream>>>(state, cnt, csr, act32, dst32,
                                              x_raw, d_out);
}